// Round 1
// baseline (141.091 us; speedup 1.0000x reference)
//
#include <hip/hip_runtime.h>

// Ensemble Q-network, fused: x[32768,23] -> (x@W1+b1).relu -> (@W2+b2).relu -> @W3+b3
// for N=10 nets. Strategy: bf16 MFMA (16x16x32) with fp32 accum; weights pre-packed
// into MFMA B-fragment order in d_ws so B-frags are single coalesced 16B loads.

typedef __attribute__((ext_vector_type(8))) short bf16x8;   // 8 bf16 in 4 VGPRs
typedef __attribute__((ext_vector_type(4))) float f32x4;    // MFMA C/D

#define B_TOTAL 32768
#define NQ 10
#define HDIM 256
#define BT 128            // batch rows per block

// round-to-nearest-even fp32 -> bf16 (explicit, to not depend on lib rounding mode)
__device__ __forceinline__ unsigned short f2bf(float f) {
  unsigned int u = __float_as_uint(f);
  u = u + 0x7FFFu + ((u >> 16) & 1u);
  return (unsigned short)(u >> 16);
}
__device__ __forceinline__ float bf2f(unsigned short h) {
  return __uint_as_float(((unsigned int)h) << 16);
}

// ---- pack kernels (run every launch; ~10us total, all tiny) ----

// xp[b][k] bf16, k in [0,32): concat(state[17], action[6]), zero-padded to 32
__global__ void pack_x_kernel(const float* __restrict__ state,
                              const float* __restrict__ action,
                              unsigned short* __restrict__ xp) {
  int t = blockIdx.x * 256 + threadIdx.x;
  if (t >= B_TOTAL * 32) return;
  int b = t >> 5, k = t & 31;
  float v = 0.f;
  if (k < 17) v = state[b * 17 + k];
  else if (k < 23) v = action[b * 6 + (k - 17)];
  xp[t] = f2bf(v);
}

// B-fragment order for mfma_f32_16x16x32_bf16:
//   frag element j of lane L holds B[k][c] with c = ct*16 + (L&15), k = kt*32 + (L>>4)*8 + j
// w1p layout: [n][ct=16][lane=64][j=8]  (single kt: K=23 padded to 32)
__global__ void pack_w1_kernel(const float* __restrict__ W1, unsigned short* __restrict__ w1p) {
  int t = blockIdx.x * 256 + threadIdx.x;          // N*16*64 = 10240
  if (t >= NQ * 16 * 64) return;
  int lane = t & 63;
  int ct = (t >> 6) & 15;
  int n = t >> 10;
  int c = ct * 16 + (lane & 15);
  int q = lane >> 4;
#pragma unroll
  for (int j = 0; j < 8; j++) {
    int k = q * 8 + j;
    float v = (k < 23) ? W1[(n * 23 + k) * 256 + c] : 0.f;
    w1p[(size_t)t * 8 + j] = f2bf(v);
  }
}

// w2p layout: [n][kt=8][ct=16][lane=64][j=8]
__global__ void pack_w2_kernel(const float* __restrict__ W2, unsigned short* __restrict__ w2p) {
  int t = blockIdx.x * 256 + threadIdx.x;          // N*8*16*64 = 81920
  if (t >= NQ * 8 * 16 * 64) return;
  int lane = t & 63;
  int ct = (t >> 6) & 15;
  int kt = (t >> 10) & 7;
  int n = t >> 13;
  int c = ct * 16 + (lane & 15);
  int q = lane >> 4;
#pragma unroll
  for (int j = 0; j < 8; j++) {
    int k = kt * 32 + q * 8 + j;
    w2p[(size_t)t * 8 + j] = f2bf(W2[((size_t)n * 256 + k) * 256 + c]);
  }
}

// ---- fused MLP kernel ----
// grid: NQ * (B_TOTAL/BT) = 2560 blocks, 256 threads (4 waves).
// Per wave: all 8 M-tiles x 4 of 16 N-coltiles. acc = 8*4*4 = 128 VGPRs.
// LDS: xs 10.0KB + h1 66.0KB + w3s 1KB = 78.8KB -> 2 blocks/CU.
__global__ __launch_bounds__(256, 2) void fused_ensemble_kernel(
    const unsigned short* __restrict__ xp,
    const unsigned short* __restrict__ w1p,
    const float* __restrict__ b1,
    const unsigned short* __restrict__ w2p,
    const float* __restrict__ b2,
    const float* __restrict__ W3,
    const float* __restrict__ b3,
    float* __restrict__ out) {
  __shared__ __align__(16) unsigned short xs[BT * 40];    // x tile, row stride 40 (pad: 2-way banks, free)
  __shared__ __align__(16) unsigned short h1s[BT * 264];  // h1 (then h2) bf16, stride 264 (132 words % 32 = 4 -> 2-way)
  __shared__ float w3s[HDIM];

  const int tid = threadIdx.x;
  const int lane = tid & 63;
  const int wave = tid >> 6;
  const int m = lane & 15;   // A-row / D-col index
  const int q = lane >> 4;   // quad: k-block for A/B, row-block for D

  const int n = blockIdx.x >> 8;          // B_TOTAL/BT = 256 tiles per net
  const int tile = blockIdx.x & 255;
  const int row0 = tile * BT;

  // stage x tile: 128 rows x 32 bf16 = 512 uint4 loads, fully coalesced
  {
    const uint4* src = (const uint4*)(xp + (size_t)row0 * 32);
#pragma unroll
    for (int i = 0; i < 2; i++) {
      int idx = tid + i * 256;            // 0..511
      int r = idx >> 2, c4 = idx & 3;
      uint4 v = src[idx];
      *(uint4*)&xs[r * 40 + c4 * 8] = v;
    }
  }
  if (tid < HDIM) w3s[tid] = W3[n * HDIM + tid];
  __syncthreads();

  f32x4 acc[8][4];
#pragma unroll
  for (int a = 0; a < 8; a++)
#pragma unroll
    for (int b = 0; b < 4; b++) acc[a][b] = (f32x4){0.f, 0.f, 0.f, 0.f};

  // ---- layer 1: [128,32] @ [32,256], single K-step ----
  {
    bf16x8 bfrag[4];
#pragma unroll
    for (int cti = 0; cti < 4; cti++) {
      int ct = wave * 4 + cti;
      bfrag[cti] = *(const bf16x8*)(w1p + (((size_t)n * 16 + ct) * 64 + lane) * 8);
    }
#pragma unroll
    for (int mt = 0; mt < 8; mt++) {
      bf16x8 afrag = *(const bf16x8*)&xs[(mt * 16 + m) * 40 + q * 8];
#pragma unroll
      for (int cti = 0; cti < 4; cti++)
        acc[mt][cti] = __builtin_amdgcn_mfma_f32_16x16x32_bf16(afrag, bfrag[cti], acc[mt][cti], 0, 0, 0);
    }
  }

  // epilogue 1: +b1, relu, -> h1 bf16 in LDS. D layout: col=lane&15, row=q*4+r.
#pragma unroll
  for (int cti = 0; cti < 4; cti++) {
    int col = (wave * 4 + cti) * 16 + m;
    float bias = b1[n * HDIM + col];
#pragma unroll
    for (int mt = 0; mt < 8; mt++)
#pragma unroll
      for (int r = 0; r < 4; r++) {
        float v = acc[mt][cti][r] + bias;
        h1s[(mt * 16 + q * 4 + r) * 264 + col] = f2bf(v > 0.f ? v : 0.f);
      }
  }
  __syncthreads();

  // ---- layer 2: [128,256] @ [256,256], 8 K-steps, B-frags streamed from L2 ----
#pragma unroll
  for (int a = 0; a < 8; a++)
#pragma unroll
    for (int b = 0; b < 4; b++) acc[a][b] = (f32x4){0.f, 0.f, 0.f, 0.f};

  const unsigned short* w2n = w2p + (size_t)n * 8 * 16 * 512;
  bf16x8 bcur[4], bnxt[4];
#pragma unroll
  for (int cti = 0; cti < 4; cti++)
    bcur[cti] = *(const bf16x8*)(w2n + (((size_t)(wave * 4 + cti)) * 64 + lane) * 8);

  for (int kt = 0; kt < 8; kt++) {
    if (kt < 7) {
#pragma unroll
      for (int cti = 0; cti < 4; cti++)
        bnxt[cti] = *(const bf16x8*)(w2n + (((size_t)(kt + 1) * 16 + wave * 4 + cti) * 64 + lane) * 8);
    }
    bf16x8 afrag[8];
#pragma unroll
    for (int mt = 0; mt < 8; mt++)
      afrag[mt] = *(const bf16x8*)&h1s[(mt * 16 + m) * 264 + kt * 32 + q * 8];
#pragma unroll
    for (int mt = 0; mt < 8; mt++)
#pragma unroll
      for (int cti = 0; cti < 4; cti++)
        acc[mt][cti] = __builtin_amdgcn_mfma_f32_16x16x32_bf16(afrag[mt], bcur[cti], acc[mt][cti], 0, 0, 0);
#pragma unroll
    for (int cti = 0; cti < 4; cti++) bcur[cti] = bnxt[cti];
  }
  __syncthreads();  // all h1 reads done before overwrite

  // epilogue 2: +b2, relu, -> h2 bf16 (reuse h1 buffer)
#pragma unroll
  for (int cti = 0; cti < 4; cti++) {
    int col = (wave * 4 + cti) * 16 + m;
    float bias = b2[n * HDIM + col];
#pragma unroll
    for (int mt = 0; mt < 8; mt++)
#pragma unroll
      for (int r = 0; r < 4; r++) {
        float v = acc[mt][cti][r] + bias;
        h1s[(mt * 16 + q * 4 + r) * 264 + col] = f2bf(v > 0.f ? v : 0.f);
      }
  }
  __syncthreads();

  // ---- layer 3: out[row] = h2[row,:] . W3 + b3, 2 threads per row ----
  {
    int row = tid >> 1;
    int half = tid & 1;
    const unsigned short* hrow = &h1s[row * 264 + half * 128];
    const float* wrow = &w3s[half * 128];
    float s = 0.f;
#pragma unroll
    for (int i = 0; i < 16; i++) {
      bf16x8 hv = *(const bf16x8*)(hrow + i * 8);
#pragma unroll
      for (int j = 0; j < 8; j++)
        s += bf2f((unsigned short)hv[j]) * wrow[i * 8 + j];
    }
    s += __shfl_xor(s, 1);
    if (half == 0) out[(size_t)n * B_TOTAL + row0 + row] = s + b3[n];
  }
}

extern "C" void kernel_launch(void* const* d_in, const int* in_sizes, int n_in,
                              void* d_out, int out_size, void* d_ws, size_t ws_size,
                              hipStream_t stream) {
  const float* state  = (const float*)d_in[0];
  const float* action = (const float*)d_in[1];
  const float* W1 = (const float*)d_in[2];
  const float* b1 = (const float*)d_in[3];
  const float* W2 = (const float*)d_in[4];
  const float* b2 = (const float*)d_in[5];
  const float* W3 = (const float*)d_in[6];
  const float* b3 = (const float*)d_in[7];
  float* out = (float*)d_out;

  unsigned short* xp  = (unsigned short*)d_ws;                                  // 2,097,152 B
  unsigned short* w1p = (unsigned short*)((char*)d_ws + 2097152);               //   163,840 B
  unsigned short* w2p = (unsigned short*)((char*)d_ws + 2097152 + 163840);      // 1,310,720 B

  pack_x_kernel<<<(B_TOTAL * 32) / 256, 256, 0, stream>>>(state, action, xp);
  pack_w1_kernel<<<40, 256, 0, stream>>>(W1, w1p);
  pack_w2_kernel<<<320, 256, 0, stream>>>(W2, w2p);
  fused_ensemble_kernel<<<NQ * (B_TOTAL / BT), 256, 0, stream>>>(
      xp, w1p, b1, w2p, b2, W3, b3, out);
}

// Round 2
// 132.472 us; speedup vs baseline: 1.0651x; 1.0651x over previous
//
#include <hip/hip_runtime.h>
#include <hip/hip_bf16.h>

// Ensemble Q-network, fused, TRANSPOSED formulation: everything computed as
// [features x batch] so MFMA C/D layout (lane: fixed col, 4 consecutive rows)
// matches the next layer's k-iteration --> vectorized LDS epilogues.
//   h1^T = relu(W1^T x^T + b1),  h2^T = relu(W2^T h1^T + b2),  out = W3^T h2^T + b3
// Weights pre-packed into MFMA A-fragment order (one pack kernel); x staged
// in-block. bf16 inputs, fp32 accumulate.

typedef __attribute__((ext_vector_type(8))) short bf16x8;   // 8 bf16 (4 VGPRs)
typedef __attribute__((ext_vector_type(4))) float f32x4;    // MFMA C/D

#define B_TOTAL 32768
#define NQ 10
#define HDIM 256
#define BT 128             // batch cols per block
#define XS_STRIDE 40       // shorts; 80B row (16B-aligned), 20-word stride
#define H_STRIDE 264       // shorts; 528B row (16B-aligned), 132-word stride

#define W1P_ELEMS (NQ * 16 * 64 * 8)        // [n][mt16][lane64][j8]
#define W2P_ELEMS (NQ * 8 * 16 * 64 * 8)    // [n][kt8][mt16][lane64][j8]
#define W3P_ELEMS (NQ * 8 * 64 * 8)         // [n][kt8][lane64][j8] (rows 1..15 zero)

__device__ __forceinline__ unsigned short f2bf(float f) {
  unsigned int u = __float_as_uint(f);
  u = u + 0x7FFFu + ((u >> 16) & 1u);
  return (unsigned short)(u >> 16);
}

__device__ __forceinline__ unsigned int pk2bf(float a, float b) {
  union { __hip_bfloat162 h; unsigned int u; } cv;
  cv.h = __float22bfloat162_rn(make_float2(a, b));
  return cv.u;
}

// ---- single pack kernel: W1^T, W2^T, W3^T into MFMA A-fragment order ----
// A-frag (16x16x32): lane holds A[m=lane&15][k=q*8+j], 8 contiguous shorts.
__global__ void pack_weights_kernel(const float* __restrict__ W1,
                                    const float* __restrict__ W2,
                                    const float* __restrict__ W3,
                                    unsigned short* __restrict__ w1p,
                                    unsigned short* __restrict__ w2p,
                                    unsigned short* __restrict__ w3p) {
  int t = blockIdx.x * 256 + threadIdx.x;     // 380 blocks * 256 = 97280 exactly
  const int NW1 = NQ * 16 * 64;               // 10240
  const int NW2 = NQ * 8 * 16 * 64;           // 81920
  if (t < NW1) {
    int lane = t & 63, mt = (t >> 6) & 15, n = t >> 10;
    int m = lane & 15, q = lane >> 4;
    int outc = mt * 16 + m;
#pragma unroll
    for (int j = 0; j < 8; j++) {
      int k = q * 8 + j;                                   // input-feature index
      float v = (k < 23) ? W1[(n * 23 + k) * 256 + outc] : 0.f;
      w1p[(size_t)t * 8 + j] = f2bf(v);
    }
  } else if (t < NW1 + NW2) {
    int u = t - NW1;
    int lane = u & 63, mt = (u >> 6) & 15, kt = (u >> 10) & 7, n = u >> 13;
    int m = lane & 15, q = lane >> 4;
    int outc = mt * 16 + m;
#pragma unroll
    for (int j = 0; j < 8; j++) {
      int h = kt * 32 + q * 8 + j;
      w2p[(size_t)u * 8 + j] = f2bf(W2[((size_t)(n * 256 + h)) * 256 + outc]);
    }
  } else {
    int u = t - NW1 - NW2;                                 // < 5120
    int lane = u & 63, kt = (u >> 6) & 7, n = u >> 9;
    int m = lane & 15, q = lane >> 4;
#pragma unroll
    for (int j = 0; j < 8; j++) {
      int h = kt * 32 + q * 8 + j;
      float v = (m == 0) ? W3[n * 256 + h] : 0.f;          // only D-row 0 is real
      w3p[(size_t)u * 8 + j] = f2bf(v);
    }
  }
}

// ---- fused MLP kernel: 2560 blocks x 256 threads (4 waves), 2 blocks/CU ----
__global__ __launch_bounds__(256, 2) void fused_ensemble_kernel(
    const float* __restrict__ state,
    const float* __restrict__ action,
    const unsigned short* __restrict__ w1p,
    const float* __restrict__ b1,
    const unsigned short* __restrict__ w2p,
    const float* __restrict__ b2,
    const unsigned short* __restrict__ w3p,
    const float* __restrict__ b3,
    float* __restrict__ out) {
  __shared__ __align__(16) unsigned short xs[BT * XS_STRIDE];  // 10.0 KB
  __shared__ __align__(16) unsigned short hs[BT * H_STRIDE];   // 66.0 KB (h1^T then h2^T)

  const int tid = threadIdx.x;
  const int lane = tid & 63;
  const int wave = tid >> 6;
  const int m = lane & 15;     // frag row/col within 16
  const int q = lane >> 4;     // quad

  const int n = blockIdx.x >> 8;           // 256 tiles per net
  const int tile = blockIdx.x & 255;
  const int row0 = tile * BT;

  // ---- prologue: stage x tile as bf16, [b][k] with k contiguous ----
  {
    const float* sp = state + (size_t)row0 * 17;
    for (int i = tid; i < BT * 17; i += 256) {
      int b = i / 17, k = i - b * 17;
      xs[b * XS_STRIDE + k] = f2bf(sp[i]);
    }
    const float* ap = action + (size_t)row0 * 6;
    for (int i = tid; i < BT * 6; i += 256) {
      int b = i / 6, k = i - b * 6;
      xs[b * XS_STRIDE + 17 + k] = f2bf(ap[i]);
    }
    for (int i = tid; i < BT * 9; i += 256) {              // zero-pad k=23..31
      int b = i / 9, k = i - b * 9;
      xs[b * XS_STRIDE + 23 + k] = 0;
    }
  }
  __syncthreads();

  f32x4 acc[4][8];   // [mt][nt]: wave owns out-rows [wave*64, wave*64+64), all 128 batch cols

  // ---- layer 1: D = W1^T(256x32) . x^T(32x128), single K-step ----
  {
    bf16x8 afrag[4];
#pragma unroll
    for (int mt = 0; mt < 4; mt++)
      afrag[mt] = *(const bf16x8*)(w1p + (((size_t)n * 16 + wave * 4 + mt) * 64 + lane) * 8);
#pragma unroll
    for (int mt = 0; mt < 4; mt++) {
      float4 bv = *(const float4*)&b1[n * HDIM + (wave * 4 + mt) * 16 + q * 4];
      f32x4 bi = (f32x4){bv.x, bv.y, bv.z, bv.w};
#pragma unroll
      for (int nt = 0; nt < 8; nt++) acc[mt][nt] = bi;     // bias pre-init
    }
#pragma unroll
    for (int nt = 0; nt < 8; nt++) {
      bf16x8 bfrag = *(const bf16x8*)&xs[(nt * 16 + m) * XS_STRIDE + q * 8];
#pragma unroll
      for (int mt = 0; mt < 4; mt++)
        acc[mt][nt] = __builtin_amdgcn_mfma_f32_16x16x32_bf16(afrag[mt], bfrag, acc[mt][nt], 0, 0, 0);
    }
  }

  // ---- epilogue 1: relu, pack 4 bf16 (consecutive h, same b) -> ds_write_b64 ----
#pragma unroll
  for (int mt = 0; mt < 4; mt++)
#pragma unroll
    for (int nt = 0; nt < 8; nt++) {
      f32x4 a = acc[mt][nt];
      uint2 w;
      w.x = pk2bf(fmaxf(a[0], 0.f), fmaxf(a[1], 0.f));
      w.y = pk2bf(fmaxf(a[2], 0.f), fmaxf(a[3], 0.f));
      *(uint2*)&hs[(nt * 16 + m) * H_STRIDE + (wave * 4 + mt) * 16 + q * 4] = w;
    }
  __syncthreads();

  // ---- layer 2: D = W2^T(256x256) . h1^T(256x128), 8 K-steps ----
  {
    const unsigned short* w2n = w2p + (size_t)n * (8 * 16 * 64 * 8);
    bf16x8 acur[4], anxt[4];
#pragma unroll
    for (int mt = 0; mt < 4; mt++)
      acur[mt] = *(const bf16x8*)(w2n + (((size_t)(wave * 4 + mt)) * 64 + lane) * 8);
#pragma unroll
    for (int mt = 0; mt < 4; mt++) {
      float4 bv = *(const float4*)&b2[n * HDIM + (wave * 4 + mt) * 16 + q * 4];
      f32x4 bi = (f32x4){bv.x, bv.y, bv.z, bv.w};
#pragma unroll
      for (int nt = 0; nt < 8; nt++) acc[mt][nt] = bi;
    }
#pragma unroll
    for (int kt = 0; kt < 8; kt++) {
      if (kt < 7) {
#pragma unroll
        for (int mt = 0; mt < 4; mt++)
          anxt[mt] = *(const bf16x8*)(w2n + (((size_t)(kt + 1) * 16 + wave * 4 + mt) * 64 + lane) * 8);
      }
      bf16x8 bfrag[8];
#pragma unroll
      for (int nt = 0; nt < 8; nt++)
        bfrag[nt] = *(const bf16x8*)&hs[(nt * 16 + m) * H_STRIDE + kt * 32 + q * 8];
#pragma unroll
      for (int nt = 0; nt < 8; nt++)
#pragma unroll
        for (int mt = 0; mt < 4; mt++)
          acc[mt][nt] = __builtin_amdgcn_mfma_f32_16x16x32_bf16(acur[mt], bfrag[nt], acc[mt][nt], 0, 0, 0);
#pragma unroll
      for (int mt = 0; mt < 4; mt++) acur[mt] = anxt[mt];
    }
  }
  __syncthreads();   // all h1 reads complete before overwrite

  // ---- epilogue 2: relu -> h2^T (reuse hs) ----
#pragma unroll
  for (int mt = 0; mt < 4; mt++)
#pragma unroll
    for (int nt = 0; nt < 8; nt++) {
      f32x4 a = acc[mt][nt];
      uint2 w;
      w.x = pk2bf(fmaxf(a[0], 0.f), fmaxf(a[1], 0.f));
      w.y = pk2bf(fmaxf(a[2], 0.f), fmaxf(a[3], 0.f));
      *(uint2*)&hs[(nt * 16 + m) * H_STRIDE + (wave * 4 + mt) * 16 + q * 4] = w;
    }
  __syncthreads();

  // ---- layer 3: D = W3^T(16x256, row 0 real) . h2^T(256x128) via MFMA ----
  {
    const unsigned short* w3n = w3p + (size_t)n * (8 * 64 * 8);
    f32x4 acc3[2];
    acc3[0] = (f32x4){0.f, 0.f, 0.f, 0.f};
    acc3[1] = (f32x4){0.f, 0.f, 0.f, 0.f};
#pragma unroll
    for (int kt = 0; kt < 8; kt++) {
      bf16x8 af = *(const bf16x8*)(w3n + ((size_t)kt * 64 + lane) * 8);
#pragma unroll
      for (int i = 0; i < 2; i++) {
        bf16x8 bf_ = *(const bf16x8*)&hs[((wave * 2 + i) * 16 + m) * H_STRIDE + kt * 32 + q * 8];
        acc3[i] = __builtin_amdgcn_mfma_f32_16x16x32_bf16(af, bf_, acc3[i], 0, 0, 0);
      }
    }
    if (lane < 16) {   // D row 0 lives in q==0 lanes, reg 0
      float bias = b3[n];
#pragma unroll
      for (int i = 0; i < 2; i++)
        out[(size_t)n * B_TOTAL + row0 + (wave * 2 + i) * 16 + m] = acc3[i][0] + bias;
    }
  }
}

extern "C" void kernel_launch(void* const* d_in, const int* in_sizes, int n_in,
                              void* d_out, int out_size, void* d_ws, size_t ws_size,
                              hipStream_t stream) {
  const float* state  = (const float*)d_in[0];
  const float* action = (const float*)d_in[1];
  const float* W1 = (const float*)d_in[2];
  const float* b1 = (const float*)d_in[3];
  const float* W2 = (const float*)d_in[4];
  const float* b2 = (const float*)d_in[5];
  const float* W3 = (const float*)d_in[6];
  const float* b3 = (const float*)d_in[7];
  float* out = (float*)d_out;

  unsigned short* w1p = (unsigned short*)d_ws;                                   // 163,840 B
  unsigned short* w2p = (unsigned short*)((char*)d_ws + (size_t)W1P_ELEMS * 2);  // 1,310,720 B
  unsigned short* w3p = (unsigned short*)((char*)d_ws + (size_t)(W1P_ELEMS + W2P_ELEMS) * 2); // 81,920 B

  pack_weights_kernel<<<380, 256, 0, stream>>>(W1, W2, W3, w1p, w2p, w3p);
  fused_ensemble_kernel<<<NQ * (B_TOTAL / BT), 256, 0, stream>>>(
      state, action, w1p, b1, w2p, b2, w3p, b3, out);
}

// Round 3
// 120.838 us; speedup vs baseline: 1.1676x; 1.0963x over previous
//
#include <hip/hip_runtime.h>
#include <hip/hip_bf16.h>

// Ensemble Q-network, fused, transposed ([features x batch]) formulation.
//   h1^T = relu(W1^T x^T + b1);  acc = W2^T h1^T + b2;  out = W3 . relu(acc)  (in-register)
// 512-thread blocks (8 waves), 2 blocks/CU, bf16 MFMA 16x16x32 with fp32 accum.
// h1 stored in LDS in "frag-chunk" layout [k/8][col][8] so epilogue writes (b64)
// and layer-2 B-frag reads (b128) are uniformly bank-spread and contiguous/lane.

typedef __attribute__((ext_vector_type(8))) short bf16x8;   // 8 bf16 (4 VGPRs)
typedef __attribute__((ext_vector_type(4))) float f32x4;    // MFMA C/D

#define B_TOTAL 32768
#define NQ 10
#define HDIM 256
#define BT 128             // batch cols per block
#define XS_STRIDE 40       // shorts per x row (k-padded 32 -> 40 for bank spread)

#define W1P_ELEMS (NQ * 16 * 64 * 8)        // [n][mtile16][lane64][j8]
#define W2P_ELEMS (NQ * 8 * 16 * 64 * 8)    // [n][kt8][mtile16][lane64][j8]

__device__ __forceinline__ unsigned short f2bf(float f) {
  unsigned int u = __float_as_uint(f);
  u = u + 0x7FFFu + ((u >> 16) & 1u);
  return (unsigned short)(u >> 16);
}

__device__ __forceinline__ unsigned int pk2bf(float a, float b) {
  union { __hip_bfloat162 h; unsigned int u; } cv;
  cv.h = __float22bfloat162_rn(make_float2(a, b));
  return cv.u;
}

// ---- pack W1^T / W2^T into MFMA A-fragment order; uint4 stores ----
__global__ void pack_weights_kernel(const float* __restrict__ W1,
                                    const float* __restrict__ W2,
                                    unsigned short* __restrict__ w1p,
                                    unsigned short* __restrict__ w2p) {
  int t = blockIdx.x * 256 + threadIdx.x;     // 360 * 256 = 92160 exactly
  const int NW1 = NQ * 16 * 64;               // 10240
  if (t < NW1) {
    int lane = t & 63, mt = (t >> 6) & 15, n = t >> 10;
    int m = lane & 15, q = lane >> 4;
    int outc = mt * 16 + m;
    unsigned short v[8];
#pragma unroll
    for (int j = 0; j < 8; j++) {
      int k = q * 8 + j;
      v[j] = (k < 23) ? f2bf(W1[(n * 23 + k) * 256 + outc]) : (unsigned short)0;
    }
    *(uint4*)&w1p[(size_t)t * 8] = *(const uint4*)v;
  } else {
    int u = t - NW1;                          // < 81920
    int lane = u & 63, mt = (u >> 6) & 15, kt = (u >> 10) & 7, n = u >> 13;
    int m = lane & 15, q = lane >> 4;
    int outc = mt * 16 + m;
    unsigned short v[8];
#pragma unroll
    for (int j = 0; j < 8; j++) {
      int h = kt * 32 + q * 8 + j;
      v[j] = f2bf(W2[((size_t)(n * 256 + h)) * 256 + outc]);
    }
    *(uint4*)&w2p[(size_t)u * 8] = *(const uint4*)v;
  }
}

// ---- fused MLP: 2560 blocks x 512 threads (8 waves), 2 blocks/CU ----
__global__ __launch_bounds__(512, 4) void fused_ensemble_kernel(
    const float* __restrict__ state,
    const float* __restrict__ action,
    const unsigned short* __restrict__ w1p,
    const float* __restrict__ b1,
    const unsigned short* __restrict__ w2p,
    const float* __restrict__ b2,
    const float* __restrict__ W3,
    const float* __restrict__ b3,
    float* __restrict__ out) {
  __shared__ __align__(16) unsigned short xs[BT * XS_STRIDE];   // 10.0 KB (reused as reduce buf)
  __shared__ __align__(16) unsigned short hs[32 * BT * 8];      // 64.0 KB, [kq][col][8]

  const int tid = threadIdx.x;
  const int lane = tid & 63;
  const int w = tid >> 6;      // wave 0..7; owns h-channels [w*32, w*32+32)
  const int m = lane & 15;
  const int q = lane >> 4;

  const int n = blockIdx.x >> 8;            // 256 tiles per net
  const int row0 = (blockIdx.x & 255) * BT;

  // ---- prologue: stage x tile as bf16 [b][k], k-padded to 32 ----
  {
    const float* sp = state + (size_t)row0 * 17;
    for (int i = tid; i < BT * 17; i += 512) {
      int b = i / 17, k = i - b * 17;
      xs[b * XS_STRIDE + k] = f2bf(sp[i]);
    }
    const float* ap = action + (size_t)row0 * 6;
    for (int i = tid; i < BT * 6; i += 512) {
      int b = i / 6, k = i - b * 6;
      xs[b * XS_STRIDE + 17 + k] = f2bf(ap[i]);
    }
    for (int i = tid; i < BT * 9; i += 512) {
      int b = i / 9, k = i - b * 9;
      xs[b * XS_STRIDE + 23 + k] = 0;
    }
  }
  __syncthreads();

  f32x4 acc[2][8];   // [mt][nt]; wave w -> channels w*32 + mt*16 + q*4 + r, col nt*16 + m

  // ---- layer 1: D = W1^T(256x32) . x^T(32x128), single K-step ----
  {
    bf16x8 af[2];
#pragma unroll
    for (int mt = 0; mt < 2; mt++)
      af[mt] = *(const bf16x8*)(w1p + (((size_t)n * 16 + w * 2 + mt) * 64 + lane) * 8);
#pragma unroll
    for (int mt = 0; mt < 2; mt++) {
      float4 bv = *(const float4*)&b1[n * HDIM + (w * 2 + mt) * 16 + q * 4];
      f32x4 bi = (f32x4){bv.x, bv.y, bv.z, bv.w};
#pragma unroll
      for (int nt = 0; nt < 8; nt++) acc[mt][nt] = bi;
    }
#pragma unroll
    for (int nt = 0; nt < 8; nt++) {
      bf16x8 bfr = *(const bf16x8*)&xs[(nt * 16 + m) * XS_STRIDE + q * 8];
#pragma unroll
      for (int mt = 0; mt < 2; mt++)
        acc[mt][nt] = __builtin_amdgcn_mfma_f32_16x16x32_bf16(af[mt], bfr, acc[mt][nt], 0, 0, 0);
    }
  }

  // ---- epilogue 1: relu -> h1 bf16 in frag-chunk layout; one b64 per frag ----
  {
    const int kqb = w * 4 + (q >> 1);       // + mt*2; channel chunk index
    const int joff = (q & 1) * 4;           // which half of the 8-elem chunk
#pragma unroll
    for (int mt = 0; mt < 2; mt++)
#pragma unroll
      for (int nt = 0; nt < 8; nt++) {
        f32x4 a = acc[mt][nt];
        uint2 wv;
        wv.x = pk2bf(fmaxf(a[0], 0.f), fmaxf(a[1], 0.f));
        wv.y = pk2bf(fmaxf(a[2], 0.f), fmaxf(a[3], 0.f));
        *(uint2*)&hs[(((kqb + mt * 2) * BT) + nt * 16 + m) * 8 + joff] = wv;
      }
  }
  __syncthreads();

  // ---- layer 2: acc = W2^T(256x256) . h1^T(256x128) + b2, 8 K-steps ----
  {
    const unsigned short* w2n = w2p + (size_t)n * (8 * 16 * 64 * 8);
    bf16x8 acur[2], anxt[2];
#pragma unroll
    for (int mt = 0; mt < 2; mt++)
      acur[mt] = *(const bf16x8*)(w2n + (((size_t)(w * 2 + mt)) * 64 + lane) * 8);
#pragma unroll
    for (int mt = 0; mt < 2; mt++) {
      float4 bv = *(const float4*)&b2[n * HDIM + (w * 2 + mt) * 16 + q * 4];
      f32x4 bi = (f32x4){bv.x, bv.y, bv.z, bv.w};
#pragma unroll
      for (int nt = 0; nt < 8; nt++) acc[mt][nt] = bi;
    }
#pragma unroll
    for (int kt = 0; kt < 8; kt++) {
      if (kt < 7) {
#pragma unroll
        for (int mt = 0; mt < 2; mt++)
          anxt[mt] = *(const bf16x8*)(w2n + (((size_t)(kt + 1) * 16 + w * 2 + mt) * 64 + lane) * 8);
      }
#pragma unroll
      for (int half = 0; half < 2; half++) {
        bf16x8 bfr[4];
#pragma unroll
        for (int i = 0; i < 4; i++) {
          int nt = half * 4 + i;
          bfr[i] = *(const bf16x8*)&hs[((kt * 4 + q) * BT + nt * 16 + m) * 8];
        }
#pragma unroll
        for (int i = 0; i < 4; i++)
#pragma unroll
          for (int mt = 0; mt < 2; mt++)
            acc[mt][half * 4 + i] = __builtin_amdgcn_mfma_f32_16x16x32_bf16(
                acur[mt], bfr[i], acc[mt][half * 4 + i], 0, 0, 0);
      }
#pragma unroll
      for (int mt = 0; mt < 2; mt++) acur[mt] = anxt[mt];
    }
  }

  // ---- layer 3 in-register: p[col] = sum_ch relu(acc_ch) * W3[ch] ----
  {
    float4 w3v[2];
#pragma unroll
    for (int mt = 0; mt < 2; mt++)
      w3v[mt] = *(const float4*)&W3[n * HDIM + (w * 2 + mt) * 16 + q * 4];
    float p[8];
#pragma unroll
    for (int nt = 0; nt < 8; nt++) {
      float s = 0.f;
#pragma unroll
      for (int mt = 0; mt < 2; mt++) {
        f32x4 a = acc[mt][nt];
        float4 wv = w3v[mt];
        s = fmaf(fmaxf(a[0], 0.f), wv.x, s);
        s = fmaf(fmaxf(a[1], 0.f), wv.y, s);
        s = fmaf(fmaxf(a[2], 0.f), wv.z, s);
        s = fmaf(fmaxf(a[3], 0.f), wv.w, s);
      }
      // reduce across the 4 q-groups (channels) for this column
      s += __shfl_xor(s, 16, 64);
      s += __shfl_xor(s, 32, 64);
      p[nt] = s;
    }
    // cross-wave reduce via small LDS buffer (reuses xs; all xs reads done pre-barrier)
    float* red = (float*)xs;   // 8 waves * 128 cols * 4B = 4 KB
    if (q == 0) {
#pragma unroll
      for (int nt = 0; nt < 8; nt++) red[w * BT + nt * 16 + m] = p[nt];
    }
    __syncthreads();
    if (tid < BT) {
      float s = b3[n];
#pragma unroll
      for (int ww = 0; ww < 8; ww++) s += red[ww * BT + tid];
      out[(size_t)n * B_TOTAL + row0 + tid] = s;
    }
  }
}

extern "C" void kernel_launch(void* const* d_in, const int* in_sizes, int n_in,
                              void* d_out, int out_size, void* d_ws, size_t ws_size,
                              hipStream_t stream) {
  const float* state  = (const float*)d_in[0];
  const float* action = (const float*)d_in[1];
  const float* W1 = (const float*)d_in[2];
  const float* b1 = (const float*)d_in[3];
  const float* W2 = (const float*)d_in[4];
  const float* b2 = (const float*)d_in[5];
  const float* W3 = (const float*)d_in[6];
  const float* b3 = (const float*)d_in[7];
  float* out = (float*)d_out;

  unsigned short* w1p = (unsigned short*)d_ws;                                   // 163,840 B
  unsigned short* w2p = (unsigned short*)((char*)d_ws + (size_t)W1P_ELEMS * 2);  // 1,310,720 B

  pack_weights_kernel<<<360, 256, 0, stream>>>(W1, W2, w1p, w2p);
  fused_ensemble_kernel<<<NQ * (B_TOTAL / BT), 512, 0, stream>>>(
      state, action, w1p, b1, w2p, b2, W3, b3, out);
}

// Round 4
// 118.700 us; speedup vs baseline: 1.1886x; 1.0180x over previous
//
#include <hip/hip_runtime.h>
#include <hip/hip_bf16.h>

// Ensemble Q-network, fused, transposed ([features x batch]).
//   h1^T = relu(W1^T x^T + b1);  acc = W2^T h1^T + b2;  out = W3 . relu(acc)  in-register.
// One pack dispatch (x -> bf16 [b][32] k-padded; W1/W2 -> MFMA A-frag order), then
// one fused dispatch: 2560 blocks x 512 threads (8 waves), 2 blocks/CU.
// Wave tile: 64 channels x 64 batch cols (mt=4, nt=4) -> halves LDS B-frag reads
// vs 32x128 tiling. Layer-1 B-frags load straight from packed global x (no prologue).

typedef __attribute__((ext_vector_type(8))) short bf16x8;   // 8 bf16 (4 VGPRs)
typedef __attribute__((ext_vector_type(4))) float f32x4;    // MFMA C/D

#define B_TOTAL 32768
#define NQ 10
#define HDIM 256
#define BT 128

#define XP_ELEMS  (B_TOTAL * 32)            // bf16 x, k-padded to 32
#define W1P_ELEMS (NQ * 16 * 64 * 8)        // [n][mtile16][lane64][j8]
#define W2P_ELEMS (NQ * 8 * 16 * 64 * 8)    // [n][kt8][mtile16][lane64][j8]

__device__ __forceinline__ unsigned short f2bf(float f) {
  unsigned int u = __float_as_uint(f);
  u = u + 0x7FFFu + ((u >> 16) & 1u);
  return (unsigned short)(u >> 16);
}

__device__ __forceinline__ unsigned int pk2bf(float a, float b) {
  union { __hip_bfloat162 h; unsigned int u; } cv;
  cv.h = __float22bfloat162_rn(make_float2(a, b));
  return cv.u;
}

// ---- single pack dispatch: x, W1^T, W2^T ----
__global__ void pack_all_kernel(const float* __restrict__ state,
                                const float* __restrict__ action,
                                const float* __restrict__ W1,
                                const float* __restrict__ W2,
                                unsigned short* __restrict__ xp,
                                unsigned short* __restrict__ w1p,
                                unsigned short* __restrict__ w2p) {
  int t = blockIdx.x * 256 + threadIdx.x;   // 872 * 256 = 223232 exactly
  const int NX  = B_TOTAL * 4;              // 131072 uint4 chunks of xp
  const int NW1 = NQ * 16 * 64;             // 10240
  if (t < NX) {
    int b = t >> 2, seg = t & 3;
    unsigned short v[8];
    if (seg < 2) {
      const float* sp = state + (size_t)b * 17 + seg * 8;
#pragma unroll
      for (int j = 0; j < 8; j++) v[j] = f2bf(sp[j]);
    } else if (seg == 2) {
      v[0] = f2bf(state[(size_t)b * 17 + 16]);
#pragma unroll
      for (int j = 0; j < 6; j++) v[1 + j] = f2bf(action[(size_t)b * 6 + j]);
      v[7] = 0;
    } else {
#pragma unroll
      for (int j = 0; j < 8; j++) v[j] = 0;
    }
    *(uint4*)&xp[(size_t)t * 8] = *(const uint4*)v;
  } else if (t < NX + NW1) {
    int u = t - NX;
    int lane = u & 63, mt = (u >> 6) & 15, n = u >> 10;
    int m = lane & 15, q = lane >> 4;
    int outc = mt * 16 + m;
    unsigned short v[8];
#pragma unroll
    for (int j = 0; j < 8; j++) {
      int k = q * 8 + j;
      v[j] = (k < 23) ? f2bf(W1[(n * 23 + k) * 256 + outc]) : (unsigned short)0;
    }
    *(uint4*)&w1p[(size_t)u * 8] = *(const uint4*)v;
  } else {
    int u = t - NX - NW1;                   // < 81920
    int lane = u & 63, mt = (u >> 6) & 15, kt = (u >> 10) & 7, n = u >> 13;
    int m = lane & 15, q = lane >> 4;
    int outc = mt * 16 + m;
    unsigned short v[8];
#pragma unroll
    for (int j = 0; j < 8; j++) {
      int h = kt * 32 + q * 8 + j;
      v[j] = f2bf(W2[((size_t)(n * 256 + h)) * 256 + outc]);
    }
    *(uint4*)&w2p[(size_t)u * 8] = *(const uint4*)v;
  }
}

// ---- fused MLP: 2560 blocks x 512 threads (8 waves), 2 blocks/CU ----
// wave w: channel group cg = w>>1 (64 ch), column group colg = w&1 (64 cols)
__global__ __launch_bounds__(512, 4) void fused_ensemble_kernel(
    const unsigned short* __restrict__ xp,
    const unsigned short* __restrict__ w1p,
    const float* __restrict__ b1,
    const unsigned short* __restrict__ w2p,
    const float* __restrict__ b2,
    const float* __restrict__ W3,
    const float* __restrict__ b3,
    float* __restrict__ out) {
  __shared__ __align__(16) unsigned short hs[32 * BT * 8];  // 64 KB, [ch/8][col][8]
  __shared__ float red[8 * 64];                             // 2 KB cross-wave reduce

  const int tid = threadIdx.x;
  const int lane = tid & 63;
  const int w = tid >> 6;
  const int m = lane & 15;
  const int q = lane >> 4;
  const int cg = w >> 1;        // channels [cg*64, cg*64+64)
  const int colg = w & 1;       // cols [colg*64, colg*64+64)

  const int n = blockIdx.x >> 8;            // 256 tiles per net
  const int row0 = (blockIdx.x & 255) * BT;

  f32x4 acc[4][4];   // [mt][nt]: ch = cg*64 + mt*16 + q*4 + r, col = colg*64 + nt*16 + m

  // ---- layer 1: single K-step (K=32, input dim 23 padded) ----
  {
    bf16x8 af[4], bfr[4];
#pragma unroll
    for (int nt = 0; nt < 4; nt++) {
      int col = row0 + colg * 64 + nt * 16 + m;       // global batch row
      bfr[nt] = *(const bf16x8*)(xp + (size_t)col * 32 + q * 8);
    }
#pragma unroll
    for (int mt = 0; mt < 4; mt++)
      af[mt] = *(const bf16x8*)(w1p + (((size_t)n * 16 + cg * 4 + mt) * 64 + lane) * 8);
#pragma unroll
    for (int mt = 0; mt < 4; mt++) {
      float4 bv = *(const float4*)&b1[n * HDIM + (cg * 4 + mt) * 16 + q * 4];
      f32x4 bi = (f32x4){bv.x, bv.y, bv.z, bv.w};
#pragma unroll
      for (int nt = 0; nt < 4; nt++) acc[mt][nt] = bi;
    }
#pragma unroll
    for (int nt = 0; nt < 4; nt++)
#pragma unroll
      for (int mt = 0; mt < 4; mt++)
        acc[mt][nt] = __builtin_amdgcn_mfma_f32_16x16x32_bf16(af[mt], bfr[nt], acc[mt][nt], 0, 0, 0);
  }

  // ---- epilogue 1: relu -> h1 bf16 frag-chunk layout; one b64 per frag ----
#pragma unroll
  for (int mt = 0; mt < 4; mt++) {
    int kq = cg * 8 + mt * 2 + (q >> 1);
    int joff = (q & 1) * 4;
#pragma unroll
    for (int nt = 0; nt < 4; nt++) {
      int col = colg * 64 + nt * 16 + m;
      f32x4 a = acc[mt][nt];
      uint2 wv;
      wv.x = pk2bf(fmaxf(a[0], 0.f), fmaxf(a[1], 0.f));
      wv.y = pk2bf(fmaxf(a[2], 0.f), fmaxf(a[3], 0.f));
      *(uint2*)&hs[((size_t)kq * BT + col) * 8 + joff] = wv;
    }
  }
  __syncthreads();

  // ---- layer 2: 8 K-steps, A-frags streamed from L2 with 1-deep prefetch ----
  {
    const unsigned short* w2n = w2p + (size_t)n * (8 * 16 * 64 * 8);
    bf16x8 acur[4], anxt[4];
#pragma unroll
    for (int mt = 0; mt < 4; mt++)
      acur[mt] = *(const bf16x8*)(w2n + (((size_t)cg * 4 + mt) * 64 + lane) * 8);
#pragma unroll
    for (int mt = 0; mt < 4; mt++) {
      float4 bv = *(const float4*)&b2[n * HDIM + (cg * 4 + mt) * 16 + q * 4];
      f32x4 bi = (f32x4){bv.x, bv.y, bv.z, bv.w};
#pragma unroll
      for (int nt = 0; nt < 4; nt++) acc[mt][nt] = bi;
    }
#pragma unroll
    for (int kt = 0; kt < 8; kt++) {
      if (kt < 7) {
#pragma unroll
        for (int mt = 0; mt < 4; mt++)
          anxt[mt] = *(const bf16x8*)(w2n + (((size_t)(kt + 1) * 16 + cg * 4 + mt) * 64 + lane) * 8);
      }
      bf16x8 bfr[4];
#pragma unroll
      for (int nt = 0; nt < 4; nt++)
        bfr[nt] = *(const bf16x8*)&hs[(((size_t)kt * 4 + q) * BT + colg * 64 + nt * 16 + m) * 8];
#pragma unroll
      for (int nt = 0; nt < 4; nt++)
#pragma unroll
        for (int mt = 0; mt < 4; mt++)
          acc[mt][nt] = __builtin_amdgcn_mfma_f32_16x16x32_bf16(acur[mt], bfr[nt], acc[mt][nt], 0, 0, 0);
#pragma unroll
      for (int mt = 0; mt < 4; mt++) acur[mt] = anxt[mt];
    }
  }

  // ---- layer 3 in-register: p[col] = sum_ch relu(acc_ch) * W3[ch]; reduce ----
  {
    float4 w3v[4];
#pragma unroll
    for (int mt = 0; mt < 4; mt++)
      w3v[mt] = *(const float4*)&W3[n * HDIM + (cg * 4 + mt) * 16 + q * 4];
    float p[4];
#pragma unroll
    for (int nt = 0; nt < 4; nt++) {
      float s = 0.f;
#pragma unroll
      for (int mt = 0; mt < 4; mt++) {
        f32x4 a = acc[mt][nt];
        float4 wv = w3v[mt];
        s = fmaf(fmaxf(a[0], 0.f), wv.x, s);
        s = fmaf(fmaxf(a[1], 0.f), wv.y, s);
        s = fmaf(fmaxf(a[2], 0.f), wv.z, s);
        s = fmaf(fmaxf(a[3], 0.f), wv.w, s);
      }
      s += __shfl_xor(s, 16, 64);   // reduce q within wave (channels)
      s += __shfl_xor(s, 32, 64);
      p[nt] = s;
    }
    if (q == 0) {
#pragma unroll
      for (int nt = 0; nt < 4; nt++) red[w * 64 + nt * 16 + m] = p[nt];
    }
    __syncthreads();
    if (tid < BT) {
      int g = tid >> 6, lc = tid & 63;       // col group, local col
      float s = b3[n];
#pragma unroll
      for (int c = 0; c < 4; c++) s += red[(c * 2 + g) * 64 + lc];
      out[(size_t)n * B_TOTAL + row0 + tid] = s;
    }
  }
}

extern "C" void kernel_launch(void* const* d_in, const int* in_sizes, int n_in,
                              void* d_out, int out_size, void* d_ws, size_t ws_size,
                              hipStream_t stream) {
  const float* state  = (const float*)d_in[0];
  const float* action = (const float*)d_in[1];
  const float* W1 = (const float*)d_in[2];
  const float* b1 = (const float*)d_in[3];
  const float* W2 = (const float*)d_in[4];
  const float* b2 = (const float*)d_in[5];
  const float* W3 = (const float*)d_in[6];
  const float* b3 = (const float*)d_in[7];
  float* out = (float*)d_out;

  unsigned short* xp  = (unsigned short*)d_ws;                                    // 2,097,152 B
  unsigned short* w1p = (unsigned short*)((char*)d_ws + (size_t)XP_ELEMS * 2);    //   163,840 B
  unsigned short* w2p = (unsigned short*)((char*)d_ws + (size_t)(XP_ELEMS + W1P_ELEMS) * 2); // 1,310,720 B

  pack_all_kernel<<<872, 256, 0, stream>>>(state, action, W1, W2, xp, w1p, w2p);
  fused_ensemble_kernel<<<NQ * (B_TOTAL / BT), 512, 0, stream>>>(
      xp, w1p, b1, w2p, b2, W3, b3, out);
}